// Round 1
// baseline (2420.867 us; speedup 1.0000x reference)
//
#include <hip/hip_runtime.h>

#define B_ 32
#define E_ 20
#define M_ 64
#define P_ 3072
#define K_ 9
#define TT 384
#define NT (P_ / TT)   // 8 tiles per batch row

// ---------------------------------------------------------------------------
// Kernel 1: one block per (b,e).
//   pass 1: y[m] = Phi[b,e,m,:] . tmp[b,e,:]  (tmp = clouds + (1-clouds)^2*surf)
//   pass 2: t2[p] = sum_m Phi[b,e,m,p] * (y[m]-d[m])
//   epilogue: s2t1 = t2*t1 (scratch for surf grad), new clouds = relu(r_clouds)
// ---------------------------------------------------------------------------
__global__ __launch_bounds__(256) void k_grad(
    const float* __restrict__ Phi,
    const float* __restrict__ dsplit,
    const float* __restrict__ surf_cur,
    const float* __restrict__ clouds_cur,
    const float* __restrict__ rho_base,
    const float* __restrict__ rho_i,
    float* __restrict__ s2t1,
    float* __restrict__ out_clouds_i)
{
    __shared__ float s_surf[P_];
    __shared__ float s_t0[P_];
    __shared__ float s_tmp[P_];
    __shared__ float s_yr[M_];

    const int bid = blockIdx.x;          // b*E_ + e
    const int b   = bid / E_;
    const int tid = threadIdx.x;

    const float* __restrict__ phi = Phi + (size_t)bid * (M_ * P_);
    const float4* __restrict__ cl4 = reinterpret_cast<const float4*>(clouds_cur + (size_t)bid * P_);
    const float4* __restrict__ sf4 = reinterpret_cast<const float4*>(surf_cur + (size_t)b * P_);

    // stage surf, t0 = 1-clouds, tmp = clouds + t0^2*surf
    for (int f = tid; f < P_ / 4; f += 256) {
        float4 c4 = cl4[f];
        float4 s4 = sf4[f];
        float4 t0, tm;
        t0.x = 1.f - c4.x;  t0.y = 1.f - c4.y;  t0.z = 1.f - c4.z;  t0.w = 1.f - c4.w;
        tm.x = c4.x + t0.x * t0.x * s4.x;
        tm.y = c4.y + t0.y * t0.y * s4.y;
        tm.z = c4.z + t0.z * t0.z * s4.z;
        tm.w = c4.w + t0.w * t0.w * s4.w;
        reinterpret_cast<float4*>(s_surf)[f] = s4;
        reinterpret_cast<float4*>(s_t0)[f]   = t0;
        reinterpret_cast<float4*>(s_tmp)[f]  = tm;
    }
    __syncthreads();

    // pass 1: each of 4 waves owns 16 m-rows
    const int wave = tid >> 6;
    const int lane = tid & 63;
    for (int m = wave; m < M_; m += 4) {
        const float4* prow = reinterpret_cast<const float4*>(phi + (size_t)m * P_);
        float acc = 0.f;
        #pragma unroll
        for (int j = 0; j < P_ / (4 * 64); ++j) {   // 12
            const int f = j * 64 + lane;
            float4 v = prow[f];
            float4 t = reinterpret_cast<const float4*>(s_tmp)[f];
            acc += v.x * t.x + v.y * t.y + v.z * t.z + v.w * t.w;
        }
        #pragma unroll
        for (int off = 32; off > 0; off >>= 1)
            acc += __shfl_down(acc, off, 64);
        if (lane == 0)
            s_yr[m] = acc - dsplit[bid * M_ + m];
    }
    __syncthreads();

    const float s = rho_base[b] * fminf(fmaxf(*rho_i, 0.1f), 3.0f);

    // pass 2: t2[p] — each thread owns 3 float4 groups (f = tid + 256*c)
    float4 a0 = {0.f, 0.f, 0.f, 0.f};
    float4 a1 = {0.f, 0.f, 0.f, 0.f};
    float4 a2 = {0.f, 0.f, 0.f, 0.f};
    for (int m = 0; m < M_; ++m) {
        const float ym = s_yr[m];
        const float4* prow = reinterpret_cast<const float4*>(phi + (size_t)m * P_);
        float4 v0 = prow[tid];
        float4 v1 = prow[tid + 256];
        float4 v2 = prow[tid + 512];
        a0.x += v0.x * ym; a0.y += v0.y * ym; a0.z += v0.z * ym; a0.w += v0.w * ym;
        a1.x += v1.x * ym; a1.y += v1.y * ym; a1.z += v1.z * ym; a1.w += v1.w * ym;
        a2.x += v2.x * ym; a2.y += v2.y * ym; a2.z += v2.z * ym; a2.w += v2.w * ym;
    }

    float4* st_out = reinterpret_cast<float4*>(s2t1 + (size_t)bid * P_);
    float4* nc_out = reinterpret_cast<float4*>(out_clouds_i + (size_t)bid * P_);

    #pragma unroll
    for (int cgrp = 0; cgrp < 3; ++cgrp) {
        const int f = tid + 256 * cgrp;
        float4 t2 = (cgrp == 0) ? a0 : (cgrp == 1) ? a1 : a2;
        float4 t0 = reinterpret_cast<const float4*>(s_t0)[f];
        float4 sv = reinterpret_cast<const float4*>(s_surf)[f];
        float4 st, nc;
#define EPI(C)                                                         \
        {                                                              \
            float t1c = t0.C * t0.C;                                   \
            st.C = t2.C * t1c;                                         \
            float gc = 2.f * t2.C * (1.f - 2.f * sv.C * t0.C);         \
            nc.C = fmaxf((1.f - t0.C) - s * gc, 0.f);                  \
        }
        EPI(x) EPI(y) EPI(z) EPI(w)
#undef EPI
        st_out[f] = st;
        nc_out[f] = nc;
    }
}

// ---------------------------------------------------------------------------
// Kernel 2: surf update + prior_surface CNN. One block per (b, P-tile of TT).
// ---------------------------------------------------------------------------
__device__ __forceinline__ void conv32(const float* inb, float* outb, const float* w,
                                       const int Wout, const int pstart)
{
    const int tid = threadIdx.x;
    const int QG = (Wout + 3) >> 2;
    const int total = 32 * QG;
    for (int g = tid; g < total; g += 256) {
        const int o = g / QG;
        const int q = g - o * QG;
        const int j0 = q << 2;
        float a0 = 0.f, a1 = 0.f, a2 = 0.f, a3 = 0.f;
        const float* wrow = w + o * 128;
        #pragma unroll 8
        for (int c = 0; c < 32; ++c) {
            const float* ip = inb + c * 400 + j0;
            const float4 i03 = *reinterpret_cast<const float4*>(ip);
            const float2 i45 = *reinterpret_cast<const float2*>(ip + 4);
            const float4 wv = *reinterpret_cast<const float4*>(wrow + c * 4);
            a0 += i03.x * wv.x + i03.y * wv.y + i03.z * wv.z;
            a1 += i03.y * wv.x + i03.z * wv.y + i03.w * wv.z;
            a2 += i03.z * wv.x + i03.w * wv.y + i45.x * wv.z;
            a3 += i03.w * wv.x + i45.x * wv.y + i45.y * wv.z;
        }
        float* op = outb + o * 400 + j0;
        const int p = pstart + j0;
        if (j0     < Wout) op[0] = (p     >= 0 && p     < P_) ? fmaxf(a0, 0.f) : 0.f;
        if (j0 + 1 < Wout) op[1] = (p + 1 >= 0 && p + 1 < P_) ? fmaxf(a1, 0.f) : 0.f;
        if (j0 + 2 < Wout) op[2] = (p + 2 >= 0 && p + 2 < P_) ? fmaxf(a2, 0.f) : 0.f;
        if (j0 + 3 < Wout) op[3] = (p + 3 >= 0 && p + 3 < P_) ? fmaxf(a3, 0.f) : 0.f;
    }
}

__global__ __launch_bounds__(256) void k_surf(
    const float* __restrict__ surf0,
    const float* __restrict__ surf_cur,
    const float* __restrict__ s2t1,
    const float* __restrict__ rho_base,
    const float* __restrict__ rho_i,
    const float* __restrict__ w1,   // [32,1,3] slice
    const float* __restrict__ w2,   // [32,32,3] slice
    const float* __restrict__ w3,   // [32,32,3] slice
    const float* __restrict__ w4,   // [1,32,3] slice
    float* __restrict__ out_surface_i)
{
    __shared__ float sx[400];
    __shared__ float bufA[32 * 400];
    __shared__ float bufB[32 * 400];
    __shared__ float sw2s[32 * 128];
    __shared__ float sw3s[32 * 128];
    __shared__ float sw1s[32 * 4];
    __shared__ float sw4s[32 * 4];

    const int tid = threadIdx.x;
    const int b  = blockIdx.x / NT;
    const int t  = blockIdx.x % NT;
    const int p0 = t * TT;

    // stage weights (tap dim padded to 4 for float4 reads)
    for (int i = tid; i < 1024; i += 256) {
        sw2s[i * 4 + 0] = w2[i * 3 + 0];
        sw2s[i * 4 + 1] = w2[i * 3 + 1];
        sw2s[i * 4 + 2] = w2[i * 3 + 2];
        sw2s[i * 4 + 3] = 0.f;
        sw3s[i * 4 + 0] = w3[i * 3 + 0];
        sw3s[i * 4 + 1] = w3[i * 3 + 1];
        sw3s[i * 4 + 2] = w3[i * 3 + 2];
        sw3s[i * 4 + 3] = 0.f;
    }
    if (tid < 32) {
        sw1s[tid * 4 + 0] = w1[tid * 3 + 0];
        sw1s[tid * 4 + 1] = w1[tid * 3 + 1];
        sw1s[tid * 4 + 2] = w1[tid * 3 + 2];
        sw1s[tid * 4 + 3] = 0.f;
        sw4s[tid * 4 + 0] = w4[tid * 3 + 0];
        sw4s[tid * 4 + 1] = w4[tid * 3 + 1];
        sw4s[tid * 4 + 2] = w4[tid * 3 + 2];
        sw4s[tid * 4 + 3] = 0.f;
    }
    // zero slack region j in [384,400) of both buffers (read-overrun safety)
    for (int i = tid; i < 32 * 16; i += 256) {
        const int c = i >> 4, j = 384 + (i & 15);
        bufA[c * 400 + j] = 0.f;
        bufB[c * 400 + j] = 0.f;
    }

    const float s = rho_base[b] * fminf(fmaxf(*rho_i, 0.1f), 3.0f);

    // r_surf (with halo 4, zero outside [0,P)) into sx
    for (int j = tid; j < 400; j += 256) {
        float v = 0.f;
        const int p = p0 + j - 4;
        if (j < TT + 8 && p >= 0 && p < P_) {
            float g = surf0[(size_t)b * P_ + p];
            #pragma unroll
            for (int e = 0; e < E_; ++e)
                g += 2.f * s2t1[((size_t)(b * E_ + e)) * P_ + p];
            v = surf_cur[(size_t)b * P_ + p] - s * g;
        }
        sx[j] = v;
    }
    __syncthreads();

    // conv1: sx (width TT+8, start p0-4) -> bufA (width TT+6, start p0-3)
    {
        const int Wout = TT + 6;          // 390
        const int QG = (Wout + 3) >> 2;   // 98
        const int pstart = p0 - 3;
        for (int g = tid; g < 32 * QG; g += 256) {
            const int o = g / QG;
            const int q = g - o * QG;
            const int j0 = q << 2;
            const float4 i03 = *reinterpret_cast<const float4*>(&sx[j0]);
            const float2 i45 = *reinterpret_cast<const float2*>(&sx[j0 + 4]);
            const float4 wv = *reinterpret_cast<const float4*>(&sw1s[o * 4]);
            float a0 = i03.x * wv.x + i03.y * wv.y + i03.z * wv.z;
            float a1 = i03.y * wv.x + i03.z * wv.y + i03.w * wv.z;
            float a2 = i03.z * wv.x + i03.w * wv.y + i45.x * wv.z;
            float a3 = i03.w * wv.x + i45.x * wv.y + i45.y * wv.z;
            float* op = &bufA[o * 400 + j0];
            const int p = pstart + j0;
            if (j0     < Wout) op[0] = (p     >= 0 && p     < P_) ? fmaxf(a0, 0.f) : 0.f;
            if (j0 + 1 < Wout) op[1] = (p + 1 >= 0 && p + 1 < P_) ? fmaxf(a1, 0.f) : 0.f;
            if (j0 + 2 < Wout) op[2] = (p + 2 >= 0 && p + 2 < P_) ? fmaxf(a2, 0.f) : 0.f;
            if (j0 + 3 < Wout) op[3] = (p + 3 >= 0 && p + 3 < P_) ? fmaxf(a3, 0.f) : 0.f;
        }
    }
    __syncthreads();
    conv32(bufA, bufB, sw2s, TT + 4, p0 - 2);   // h2
    __syncthreads();
    conv32(bufB, bufA, sw3s, TT + 2, p0 - 1);   // h3
    __syncthreads();

    // conv4 + residual + clip -> out_surface_i
    for (int g = tid; g < TT / 4; g += 256) {
        const int j0 = g << 2;
        float a0 = 0.f, a1 = 0.f, a2 = 0.f, a3 = 0.f;
        #pragma unroll 8
        for (int c = 0; c < 32; ++c) {
            const float* ip = &bufA[c * 400 + j0];
            const float4 i03 = *reinterpret_cast<const float4*>(ip);
            const float2 i45 = *reinterpret_cast<const float2*>(ip + 4);
            const float4 wv = *reinterpret_cast<const float4*>(&sw4s[c * 4]);
            a0 += i03.x * wv.x + i03.y * wv.y + i03.z * wv.z;
            a1 += i03.y * wv.x + i03.z * wv.y + i03.w * wv.z;
            a2 += i03.z * wv.x + i03.w * wv.y + i45.x * wv.z;
            a3 += i03.w * wv.x + i45.x * wv.y + i45.y * wv.z;
        }
        const float4 xr = *reinterpret_cast<const float4*>(&sx[j0 + 4]);
        float4 ov;
        ov.x = fminf(fmaxf(xr.x + fmaxf(a0, 0.f), 0.f), 1.f);
        ov.y = fminf(fmaxf(xr.y + fmaxf(a1, 0.f), 0.f), 1.f);
        ov.z = fminf(fmaxf(xr.z + fmaxf(a2, 0.f), 0.f), 1.f);
        ov.w = fminf(fmaxf(xr.w + fmaxf(a3, 0.f), 0.f), 1.f);
        *reinterpret_cast<float4*>(&out_surface_i[(size_t)b * P_ + p0 + j0]) = ov;
    }
}

// ---------------------------------------------------------------------------
extern "C" void kernel_launch(void* const* d_in, const int* in_sizes, int n_in,
                              void* d_out, int out_size, void* d_ws, size_t ws_size,
                              hipStream_t stream)
{
    (void)in_sizes; (void)n_in; (void)out_size; (void)d_ws; (void)ws_size;

    const float* dsplit   = (const float*)d_in[0];
    const float* surf0    = (const float*)d_in[1];
    const float* clouds0  = (const float*)d_in[2];
    const float* Phi      = (const float*)d_in[3];
    const float* rho_base = (const float*)d_in[4];
    const float* rho      = (const float*)d_in[5];
    const float* w1       = (const float*)d_in[6];
    const float* w2       = (const float*)d_in[7];
    const float* w3       = (const float*)d_in[8];
    const float* w4       = (const float*)d_in[9];

    float* out = (float*)d_out;
    float* out_surf_final   = out;                                   // [B,P]
    float* out_clouds_final = out + (size_t)B_ * P_;                 // [B,E,P]
    float* out_surface      = out_clouds_final + (size_t)B_ * E_ * P_;  // [K,B,P]
    float* out_clouds       = out_surface + (size_t)K_ * B_ * P_;       // [K,B,E,P]

    // scratch for t2*t1 lives in the final-clouds slot (exactly B*E*P floats);
    // the final d2d copy overwrites it afterwards.
    float* s2t1 = out_clouds_final;

    for (int i = 0; i < K_; ++i) {
        const float* scur = (i == 0) ? surf0   : out_surface + (size_t)(i - 1) * B_ * P_;
        const float* ccur = (i == 0) ? clouds0 : out_clouds + (size_t)(i - 1) * B_ * E_ * P_;

        k_grad<<<dim3(B_ * E_), dim3(256), 0, stream>>>(
            Phi, dsplit, scur, ccur, rho_base, rho + i,
            s2t1, out_clouds + (size_t)i * B_ * E_ * P_);

        k_surf<<<dim3(B_ * NT), dim3(256), 0, stream>>>(
            surf0, scur, s2t1, rho_base, rho + i,
            w1 + (size_t)i * 96, w2 + (size_t)i * 3072,
            w3 + (size_t)i * 3072, w4 + (size_t)i * 96,
            out_surface + (size_t)i * B_ * P_);
    }

    hipMemcpyAsync(out_surf_final, out_surface + (size_t)(K_ - 1) * B_ * P_,
                   (size_t)B_ * P_ * sizeof(float), hipMemcpyDeviceToDevice, stream);
    hipMemcpyAsync(out_clouds_final, out_clouds + (size_t)(K_ - 1) * B_ * E_ * P_,
                   (size_t)B_ * E_ * P_ * sizeof(float), hipMemcpyDeviceToDevice, stream);
}

// Round 2
// 1423.199 us; speedup vs baseline: 1.7010x; 1.7010x over previous
//
#include <hip/hip_runtime.h>

#define B_ 32
#define E_ 20
#define M_ 64
#define P_ 3072
#define K_ 9
#define TT 384
#define NT (P_ / TT)   // 8 tiles per batch row

typedef _Float16 half8 __attribute__((ext_vector_type(8)));

// ---------------------------------------------------------------------------
// Phi fp32 -> fp16 conversion (one pass per launch when ws fits)
// ---------------------------------------------------------------------------
__global__ __launch_bounds__(256) void k_cvt(const float* __restrict__ src,
                                             _Float16* __restrict__ dst, int n8)
{
    int i = blockIdx.x * 256 + threadIdx.x;
    const int stride = gridDim.x * 256;
    const float4* s4 = reinterpret_cast<const float4*>(src);
    half8* d8 = reinterpret_cast<half8*>(dst);
    for (; i < n8; i += stride) {
        float4 a = s4[i * 2], b = s4[i * 2 + 1];
        half8 h;
        h[0] = (_Float16)a.x; h[1] = (_Float16)a.y; h[2] = (_Float16)a.z; h[3] = (_Float16)a.w;
        h[4] = (_Float16)b.x; h[5] = (_Float16)b.y; h[6] = (_Float16)b.z; h[7] = (_Float16)b.w;
        d8[i] = h;
    }
}

// ---------------------------------------------------------------------------
// per-row dot helpers (64 lanes cooperate on one Phi row . tmp row)
// ---------------------------------------------------------------------------
__device__ __forceinline__ float dot_row(const _Float16* __restrict__ row,
                                         const float* __restrict__ s_tmp, int lane)
{
    const half8* r8 = reinterpret_cast<const half8*>(row);
    const float4* t4 = reinterpret_cast<const float4*>(s_tmp);
    float acc = 0.f;
    #pragma unroll
    for (int j = 0; j < 6; ++j) {
        const int f = j * 64 + lane;
        half8 v = r8[f];
        float4 a = t4[f * 2], b = t4[f * 2 + 1];
        acc += (float)v[0] * a.x + (float)v[1] * a.y + (float)v[2] * a.z + (float)v[3] * a.w
             + (float)v[4] * b.x + (float)v[5] * b.y + (float)v[6] * b.z + (float)v[7] * b.w;
    }
    return acc;
}

__device__ __forceinline__ float dot_row(const float* __restrict__ row,
                                         const float* __restrict__ s_tmp, int lane)
{
    const float4* r4 = reinterpret_cast<const float4*>(row);
    const float4* t4 = reinterpret_cast<const float4*>(s_tmp);
    float acc = 0.f;
    #pragma unroll
    for (int j = 0; j < 12; ++j) {
        const int f = j * 64 + lane;
        float4 v = r4[f], t = t4[f];
        acc += v.x * t.x + v.y * t.y + v.z * t.z + v.w * t.w;
    }
    return acc;
}

__device__ __forceinline__ void accum8(float* acc, const _Float16* __restrict__ p, float ym)
{
    half8 v = *reinterpret_cast<const half8*>(p);
    #pragma unroll
    for (int k = 0; k < 8; ++k) acc[k] += (float)v[k] * ym;
}

__device__ __forceinline__ void accum8(float* acc, const float* __restrict__ p, float ym)
{
    float4 a = *reinterpret_cast<const float4*>(p);
    float4 b = *reinterpret_cast<const float4*>(p + 4);
    acc[0] += a.x * ym; acc[1] += a.y * ym; acc[2] += a.z * ym; acc[3] += a.w * ym;
    acc[4] += b.x * ym; acc[5] += b.y * ym; acc[6] += b.z * ym; acc[7] += b.w * ym;
}

// ---------------------------------------------------------------------------
// Kernel 1a: y[m]-d[m]. grid = B*E*2 (m-halves), 256 threads (4 waves x 8 rows)
// ---------------------------------------------------------------------------
template <typename PT>
__global__ __launch_bounds__(256) void k_y(
    const PT* __restrict__ Phi,
    const float* __restrict__ dsplit,
    const float* __restrict__ surf_cur,
    const float* __restrict__ clouds_cur,
    float* __restrict__ yr)
{
    __shared__ float s_tmp[P_];
    const int bid = blockIdx.x >> 1;     // b*E_+e
    const int mh  = blockIdx.x & 1;
    const int b   = bid / E_;
    const int tid = threadIdx.x;

    const float4* cl4 = reinterpret_cast<const float4*>(clouds_cur + (size_t)bid * P_);
    const float4* sf4 = reinterpret_cast<const float4*>(surf_cur + (size_t)b * P_);
    for (int f = tid; f < P_ / 4; f += 256) {
        float4 c4 = cl4[f], s4 = sf4[f], tm;
        float t0x = 1.f - c4.x, t0y = 1.f - c4.y, t0z = 1.f - c4.z, t0w = 1.f - c4.w;
        tm.x = c4.x + t0x * t0x * s4.x;
        tm.y = c4.y + t0y * t0y * s4.y;
        tm.z = c4.z + t0z * t0z * s4.z;
        tm.w = c4.w + t0w * t0w * s4.w;
        reinterpret_cast<float4*>(s_tmp)[f] = tm;
    }
    __syncthreads();

    const int wave = tid >> 6, lane = tid & 63;
    const PT* phi = Phi + (size_t)bid * (M_ * P_);
    #pragma unroll
    for (int r = 0; r < 8; ++r) {
        const int mg = mh * 32 + wave * 8 + r;
        float acc = dot_row(phi + (size_t)mg * P_, s_tmp, lane);
        #pragma unroll
        for (int off = 32; off > 0; off >>= 1)
            acc += __shfl_down(acc, off, 64);
        if (lane == 0)
            yr[bid * M_ + mg] = acc - dsplit[bid * M_ + mg];
    }
}

// ---------------------------------------------------------------------------
// Kernel 1b: t2 + gradient epilogue. grid = B*E*2 (P-halves), 192 threads,
// each thread owns 8 consecutive p.
// ---------------------------------------------------------------------------
template <typename PT>
__global__ __launch_bounds__(192) void k_t2(
    const PT* __restrict__ Phi,
    const float* __restrict__ yr,
    const float* __restrict__ surf_cur,
    const float* __restrict__ clouds_cur,
    const float* __restrict__ rho_base,
    const float* __restrict__ rho_i,
    float* __restrict__ s2t1,
    float* __restrict__ out_clouds_i)
{
    __shared__ float s_yr[M_];
    const int bid = blockIdx.x >> 1;
    const int ph  = blockIdx.x & 1;
    const int b   = bid / E_;
    const int tid = threadIdx.x;

    if (tid < M_) s_yr[tid] = yr[bid * M_ + tid];
    __syncthreads();

    const int p0 = ph * 1536 + tid * 8;
    const PT* phi = Phi + (size_t)bid * (M_ * P_) + p0;

    float acc[8] = {0.f, 0.f, 0.f, 0.f, 0.f, 0.f, 0.f, 0.f};
    #pragma unroll 4
    for (int m = 0; m < M_; ++m)
        accum8(acc, phi + (size_t)m * P_, s_yr[m]);

    const float s = rho_base[b] * fminf(fmaxf(*rho_i, 0.1f), 3.0f);
    const size_t gi = (size_t)bid * P_ + p0;
    float4 c0 = *reinterpret_cast<const float4*>(clouds_cur + gi);
    float4 c1 = *reinterpret_cast<const float4*>(clouds_cur + gi + 4);
    const size_t si = (size_t)b * P_ + p0;
    float4 v0 = *reinterpret_cast<const float4*>(surf_cur + si);
    float4 v1 = *reinterpret_cast<const float4*>(surf_cur + si + 4);

    float cl[8] = {c0.x, c0.y, c0.z, c0.w, c1.x, c1.y, c1.z, c1.w};
    float sv[8] = {v0.x, v0.y, v0.z, v0.w, v1.x, v1.y, v1.z, v1.w};
    float st[8], nc[8];
    #pragma unroll
    for (int k = 0; k < 8; ++k) {
        float t0 = 1.f - cl[k];
        st[k] = acc[k] * t0 * t0;
        float gc = 2.f * acc[k] * (1.f - 2.f * sv[k] * t0);
        nc[k] = fmaxf(cl[k] - s * gc, 0.f);
    }
    reinterpret_cast<float4*>(s2t1 + gi)[0] = make_float4(st[0], st[1], st[2], st[3]);
    reinterpret_cast<float4*>(s2t1 + gi + 4)[0] = make_float4(st[4], st[5], st[6], st[7]);
    reinterpret_cast<float4*>(out_clouds_i + gi)[0] = make_float4(nc[0], nc[1], nc[2], nc[3]);
    reinterpret_cast<float4*>(out_clouds_i + gi + 4)[0] = make_float4(nc[4], nc[5], nc[6], nc[7]);
}

// ---------------------------------------------------------------------------
// Kernel 2: surf update + prior_surface CNN. One block per (b, P-tile of TT).
// conv2/conv3: register-tiled, 4 output channels x 4 j per thread.
// Weight LDS layout: [c][o][tap4] (float4 per (c,o)).
// ---------------------------------------------------------------------------
__device__ __forceinline__ void conv32_rt(const float* __restrict__ inb,
                                          float* __restrict__ outb,
                                          const float* __restrict__ w,
                                          const int Wout, const int pstart)
{
    const int tid = threadIdx.x;
    const int QG = (Wout + 3) >> 2;
    const int items = 8 * QG;
    for (int g = tid; g < items; g += 256) {
        const int oo = g / QG;
        const int q  = g - oo * QG;
        const int j0 = q << 2;
        float a[4][4];
        #pragma unroll
        for (int ol = 0; ol < 4; ++ol)
            a[ol][0] = a[ol][1] = a[ol][2] = a[ol][3] = 0.f;
        #pragma unroll 4
        for (int c = 0; c < 32; ++c) {
            const float* ip = inb + c * 400 + j0;
            const float4 i03 = *reinterpret_cast<const float4*>(ip);
            const float2 i45 = *reinterpret_cast<const float2*>(ip + 4);
            const float* wb = w + (c * 32 + oo * 4) * 4;
            #pragma unroll
            for (int ol = 0; ol < 4; ++ol) {
                const float4 wv = *reinterpret_cast<const float4*>(wb + ol * 4);
                a[ol][0] += i03.x * wv.x + i03.y * wv.y + i03.z * wv.z;
                a[ol][1] += i03.y * wv.x + i03.z * wv.y + i03.w * wv.z;
                a[ol][2] += i03.z * wv.x + i03.w * wv.y + i45.x * wv.z;
                a[ol][3] += i03.w * wv.x + i45.x * wv.y + i45.y * wv.z;
            }
        }
        const int p = pstart + j0;
        #pragma unroll
        for (int ol = 0; ol < 4; ++ol) {
            float* op = outb + (oo * 4 + ol) * 400 + j0;
            if (j0     < Wout) op[0] = (p     >= 0 && p     < P_) ? fmaxf(a[ol][0], 0.f) : 0.f;
            if (j0 + 1 < Wout) op[1] = (p + 1 >= 0 && p + 1 < P_) ? fmaxf(a[ol][1], 0.f) : 0.f;
            if (j0 + 2 < Wout) op[2] = (p + 2 >= 0 && p + 2 < P_) ? fmaxf(a[ol][2], 0.f) : 0.f;
            if (j0 + 3 < Wout) op[3] = (p + 3 >= 0 && p + 3 < P_) ? fmaxf(a[ol][3], 0.f) : 0.f;
        }
    }
}

__global__ __launch_bounds__(256) void k_surf(
    const float* __restrict__ surf0,
    const float* __restrict__ surf_cur,
    const float* __restrict__ s2t1,
    const float* __restrict__ rho_base,
    const float* __restrict__ rho_i,
    const float* __restrict__ w1,   // [32,1,3] slice
    const float* __restrict__ w2,   // [32,32,3] slice
    const float* __restrict__ w3,   // [32,32,3] slice
    const float* __restrict__ w4,   // [1,32,3] slice
    float* __restrict__ out_surface_i)
{
    __shared__ float sx[400];
    __shared__ float bufA[32 * 400];
    __shared__ float bufB[32 * 400];
    __shared__ float sw2s[32 * 32 * 4];   // [c][o][tap4]
    __shared__ float sw3s[32 * 32 * 4];
    __shared__ float sw1s[32 * 4];        // [o][tap4]
    __shared__ float sw4s[32 * 4];        // [c][tap4]

    const int tid = threadIdx.x;
    const int b  = blockIdx.x / NT;
    const int t  = blockIdx.x % NT;
    const int p0 = t * TT;

    // stage weights; w2/w3 transposed to [c][o][tap4]
    for (int i = tid; i < 1024; i += 256) {
        const int c = i >> 5, o = i & 31;
        const int src = (o * 32 + c) * 3;
        sw2s[i * 4 + 0] = w2[src + 0];
        sw2s[i * 4 + 1] = w2[src + 1];
        sw2s[i * 4 + 2] = w2[src + 2];
        sw2s[i * 4 + 3] = 0.f;
        sw3s[i * 4 + 0] = w3[src + 0];
        sw3s[i * 4 + 1] = w3[src + 1];
        sw3s[i * 4 + 2] = w3[src + 2];
        sw3s[i * 4 + 3] = 0.f;
    }
    if (tid < 32) {
        sw1s[tid * 4 + 0] = w1[tid * 3 + 0];
        sw1s[tid * 4 + 1] = w1[tid * 3 + 1];
        sw1s[tid * 4 + 2] = w1[tid * 3 + 2];
        sw1s[tid * 4 + 3] = 0.f;
        sw4s[tid * 4 + 0] = w4[tid * 3 + 0];
        sw4s[tid * 4 + 1] = w4[tid * 3 + 1];
        sw4s[tid * 4 + 2] = w4[tid * 3 + 2];
        sw4s[tid * 4 + 3] = 0.f;
    }
    // zero slack region j in [384,400)
    for (int i = tid; i < 32 * 16; i += 256) {
        const int c = i >> 4, j = 384 + (i & 15);
        bufA[c * 400 + j] = 0.f;
        bufB[c * 400 + j] = 0.f;
    }

    const float s = rho_base[b] * fminf(fmaxf(*rho_i, 0.1f), 3.0f);

    // r_surf (halo 4, zero outside [0,P))
    for (int j = tid; j < 400; j += 256) {
        float v = 0.f;
        const int p = p0 + j - 4;
        if (j < TT + 8 && p >= 0 && p < P_) {
            float g = surf0[(size_t)b * P_ + p];
            #pragma unroll
            for (int e = 0; e < E_; ++e)
                g += 2.f * s2t1[((size_t)(b * E_ + e)) * P_ + p];
            v = surf_cur[(size_t)b * P_ + p] - s * g;
        }
        sx[j] = v;
    }
    __syncthreads();

    // conv1
    {
        const int Wout = TT + 6;
        const int QG = (Wout + 3) >> 2;
        const int pstart = p0 - 3;
        for (int g = tid; g < 32 * QG; g += 256) {
            const int o = g / QG;
            const int q = g - o * QG;
            const int j0 = q << 2;
            const float4 i03 = *reinterpret_cast<const float4*>(&sx[j0]);
            const float2 i45 = *reinterpret_cast<const float2*>(&sx[j0 + 4]);
            const float4 wv = *reinterpret_cast<const float4*>(&sw1s[o * 4]);
            float a0 = i03.x * wv.x + i03.y * wv.y + i03.z * wv.z;
            float a1 = i03.y * wv.x + i03.z * wv.y + i03.w * wv.z;
            float a2 = i03.z * wv.x + i03.w * wv.y + i45.x * wv.z;
            float a3 = i03.w * wv.x + i45.x * wv.y + i45.y * wv.z;
            float* op = &bufA[o * 400 + j0];
            const int p = pstart + j0;
            if (j0     < Wout) op[0] = (p     >= 0 && p     < P_) ? fmaxf(a0, 0.f) : 0.f;
            if (j0 + 1 < Wout) op[1] = (p + 1 >= 0 && p + 1 < P_) ? fmaxf(a1, 0.f) : 0.f;
            if (j0 + 2 < Wout) op[2] = (p + 2 >= 0 && p + 2 < P_) ? fmaxf(a2, 0.f) : 0.f;
            if (j0 + 3 < Wout) op[3] = (p + 3 >= 0 && p + 3 < P_) ? fmaxf(a3, 0.f) : 0.f;
        }
    }
    __syncthreads();
    conv32_rt(bufA, bufB, sw2s, TT + 4, p0 - 2);
    __syncthreads();
    conv32_rt(bufB, bufA, sw3s, TT + 2, p0 - 1);
    __syncthreads();

    // conv4 + residual + clip
    for (int g = tid; g < TT / 4; g += 256) {
        const int j0 = g << 2;
        float a0 = 0.f, a1 = 0.f, a2 = 0.f, a3 = 0.f;
        #pragma unroll 8
        for (int c = 0; c < 32; ++c) {
            const float* ip = &bufA[c * 400 + j0];
            const float4 i03 = *reinterpret_cast<const float4*>(ip);
            const float2 i45 = *reinterpret_cast<const float2*>(ip + 4);
            const float4 wv = *reinterpret_cast<const float4*>(&sw4s[c * 4]);
            a0 += i03.x * wv.x + i03.y * wv.y + i03.z * wv.z;
            a1 += i03.y * wv.x + i03.z * wv.y + i03.w * wv.z;
            a2 += i03.z * wv.x + i03.w * wv.y + i45.x * wv.z;
            a3 += i03.w * wv.x + i45.x * wv.y + i45.y * wv.z;
        }
        const float4 xr = *reinterpret_cast<const float4*>(&sx[j0 + 4]);
        float4 ov;
        ov.x = fminf(fmaxf(xr.x + fmaxf(a0, 0.f), 0.f), 1.f);
        ov.y = fminf(fmaxf(xr.y + fmaxf(a1, 0.f), 0.f), 1.f);
        ov.z = fminf(fmaxf(xr.z + fmaxf(a2, 0.f), 0.f), 1.f);
        ov.w = fminf(fmaxf(xr.w + fmaxf(a3, 0.f), 0.f), 1.f);
        *reinterpret_cast<float4*>(&out_surface_i[(size_t)b * P_ + p0 + j0]) = ov;
    }
}

// ---------------------------------------------------------------------------
template <typename PT>
static void run_loop(const PT* Phi,
                     const float* dsplit, const float* surf0, const float* clouds0,
                     const float* rho_base, const float* rho,
                     const float* w1, const float* w2, const float* w3, const float* w4,
                     float* yr, float* s2t1,
                     float* out_surface, float* out_clouds, hipStream_t stream)
{
    for (int i = 0; i < K_; ++i) {
        const float* scur = (i == 0) ? surf0   : out_surface + (size_t)(i - 1) * B_ * P_;
        const float* ccur = (i == 0) ? clouds0 : out_clouds + (size_t)(i - 1) * B_ * E_ * P_;

        k_y<PT><<<dim3(B_ * E_ * 2), dim3(256), 0, stream>>>(
            Phi, dsplit, scur, ccur, yr);

        k_t2<PT><<<dim3(B_ * E_ * 2), dim3(192), 0, stream>>>(
            Phi, yr, scur, ccur, rho_base, rho + i,
            s2t1, out_clouds + (size_t)i * B_ * E_ * P_);

        k_surf<<<dim3(B_ * NT), dim3(256), 0, stream>>>(
            surf0, scur, s2t1, rho_base, rho + i,
            w1 + (size_t)i * 96, w2 + (size_t)i * 3072,
            w3 + (size_t)i * 3072, w4 + (size_t)i * 96,
            out_surface + (size_t)i * B_ * P_);
    }
}

extern "C" void kernel_launch(void* const* d_in, const int* in_sizes, int n_in,
                              void* d_out, int out_size, void* d_ws, size_t ws_size,
                              hipStream_t stream)
{
    (void)in_sizes; (void)n_in; (void)out_size;

    const float* dsplit   = (const float*)d_in[0];
    const float* surf0    = (const float*)d_in[1];
    const float* clouds0  = (const float*)d_in[2];
    const float* Phi      = (const float*)d_in[3];
    const float* rho_base = (const float*)d_in[4];
    const float* rho      = (const float*)d_in[5];
    const float* w1       = (const float*)d_in[6];
    const float* w2       = (const float*)d_in[7];
    const float* w3       = (const float*)d_in[8];
    const float* w4       = (const float*)d_in[9];

    float* out = (float*)d_out;
    float* out_surf_final   = out;                                      // [B,P]
    float* out_clouds_final = out + (size_t)B_ * P_;                    // [B,E,P]
    float* out_surface      = out_clouds_final + (size_t)B_ * E_ * P_;  // [K,B,P]
    float* out_clouds       = out_surface + (size_t)K_ * B_ * P_;       // [K,B,E,P]

    // scratch: yr (B*E*M floats) in the surf_final slot (B*P >= B*E*M),
    // s2t1 (B*E*P floats) in the clouds_final slot; both overwritten by the
    // final d2d copies.
    float* yr   = out_surf_final;
    float* s2t1 = out_clouds_final;

    const size_t PHI_N = (size_t)B_ * E_ * M_ * P_;   // 125,829,120

    if (ws_size >= PHI_N * sizeof(_Float16)) {
        _Float16* phi16 = (_Float16*)d_ws;
        k_cvt<<<dim3(4096), dim3(256), 0, stream>>>(Phi, phi16, (int)(PHI_N / 8));
        run_loop<_Float16>(phi16, dsplit, surf0, clouds0, rho_base, rho,
                           w1, w2, w3, w4, yr, s2t1, out_surface, out_clouds, stream);
    } else {
        run_loop<float>(Phi, dsplit, surf0, clouds0, rho_base, rho,
                        w1, w2, w3, w4, yr, s2t1, out_surface, out_clouds, stream);
    }

    hipMemcpyAsync(out_surf_final, out_surface + (size_t)(K_ - 1) * B_ * P_,
                   (size_t)B_ * P_ * sizeof(float), hipMemcpyDeviceToDevice, stream);
    hipMemcpyAsync(out_clouds_final, out_clouds + (size_t)(K_ - 1) * B_ * E_ * P_,
                   (size_t)B_ * E_ * P_ * sizeof(float), hipMemcpyDeviceToDevice, stream);
}

// Round 3
// 1049.801 us; speedup vs baseline: 2.3060x; 1.3557x over previous
//
#include <hip/hip_runtime.h>

#define B_ 32
#define E_ 20
#define M_ 64
#define P_ 3072
#define K_ 9
#define TT 384
#define NT (P_ / TT)   // 8 tiles per batch row

#define PHI_SCALE 65536.0f
#define PHI_INV   (1.0f / 65536.0f)

typedef float floatx2 __attribute__((ext_vector_type(2)));

__device__ __forceinline__ unsigned int pack4_fp8(float f0, float f1, float f2, float f3)
{
    int w = 0;
    w = __builtin_amdgcn_cvt_pk_fp8_f32(f0, f1, w, false);
    w = __builtin_amdgcn_cvt_pk_fp8_f32(f2, f3, w, true);
    return (unsigned int)w;
}

// ---------------------------------------------------------------------------
// Kernel 1a: y[m]-d[m]. grid = B*E*2 (m-halves), 256 threads (4 waves x 8 rows)
// MODE 0: read fp32 Phi.  MODE 1: read fp32 Phi, also emit fp8 (iter 0).
// MODE 2: read fp8 Phi.
// ---------------------------------------------------------------------------
template <int MODE>
__global__ __launch_bounds__(256) void k_y(
    const float* __restrict__ PhiF,
    const unsigned char* __restrict__ Phi8,
    unsigned char* __restrict__ Phi8out,
    const float* __restrict__ dsplit,
    const float* __restrict__ surf_cur,
    const float* __restrict__ clouds_cur,
    float* __restrict__ yr)
{
    __shared__ float s_tmp[P_];
    const int bid = blockIdx.x >> 1;     // b*E_+e
    const int mh  = blockIdx.x & 1;
    const int b   = bid / E_;
    const int tid = threadIdx.x;

    const float4* cl4 = reinterpret_cast<const float4*>(clouds_cur + (size_t)bid * P_);
    const float4* sf4 = reinterpret_cast<const float4*>(surf_cur + (size_t)b * P_);
    for (int f = tid; f < P_ / 4; f += 256) {
        float4 c4 = cl4[f], s4 = sf4[f], tm;
        float t0x = 1.f - c4.x, t0y = 1.f - c4.y, t0z = 1.f - c4.z, t0w = 1.f - c4.w;
        tm.x = c4.x + t0x * t0x * s4.x;
        tm.y = c4.y + t0y * t0y * s4.y;
        tm.z = c4.z + t0z * t0z * s4.z;
        tm.w = c4.w + t0w * t0w * s4.w;
        reinterpret_cast<float4*>(s_tmp)[f] = tm;
    }
    __syncthreads();

    const int wave = tid >> 6, lane = tid & 63;
    const size_t base = (size_t)bid * (M_ * P_);

    #pragma unroll
    for (int r = 0; r < 8; ++r) {
        const int mg = mh * 32 + wave * 8 + r;
        float acc = 0.f;
        if constexpr (MODE != 2) {
            const float4* prow = reinterpret_cast<const float4*>(PhiF + base + (size_t)mg * P_);
            unsigned int* orow = reinterpret_cast<unsigned int*>(Phi8out + base + (size_t)mg * P_);
            #pragma unroll
            for (int j = 0; j < 12; ++j) {
                const int f = j * 64 + lane;
                float4 v = prow[f];
                float4 t = reinterpret_cast<const float4*>(s_tmp)[f];
                acc += v.x * t.x + v.y * t.y + v.z * t.z + v.w * t.w;
                if constexpr (MODE == 1) {
                    orow[f] = pack4_fp8(v.x * PHI_SCALE, v.y * PHI_SCALE,
                                        v.z * PHI_SCALE, v.w * PHI_SCALE);
                }
            }
        } else {
            const uint2* prow = reinterpret_cast<const uint2*>(Phi8 + base + (size_t)mg * P_);
            #pragma unroll
            for (int j = 0; j < 6; ++j) {
                const int f = j * 64 + lane;
                uint2 w = prow[f];
                floatx2 l0 = __builtin_amdgcn_cvt_pk_f32_fp8((int)w.x, false);
                floatx2 h0 = __builtin_amdgcn_cvt_pk_f32_fp8((int)w.x, true);
                floatx2 l1 = __builtin_amdgcn_cvt_pk_f32_fp8((int)w.y, false);
                floatx2 h1 = __builtin_amdgcn_cvt_pk_f32_fp8((int)w.y, true);
                float4 a = reinterpret_cast<const float4*>(s_tmp)[2 * f];
                float4 bb = reinterpret_cast<const float4*>(s_tmp)[2 * f + 1];
                acc += l0.x * a.x + l0.y * a.y + h0.x * a.z + h0.y * a.w
                     + l1.x * bb.x + l1.y * bb.y + h1.x * bb.z + h1.y * bb.w;
            }
        }
        #pragma unroll
        for (int off = 32; off > 0; off >>= 1)
            acc += __shfl_down(acc, off, 64);
        if (lane == 0) {
            if constexpr (MODE == 2) acc *= PHI_INV;
            yr[bid * M_ + mg] = acc - dsplit[bid * M_ + mg];
        }
    }
}

// ---------------------------------------------------------------------------
// Kernel 1b (fp8): t2 + gradient epilogue. grid = B*E*2 (P-halves), 192 thr,
// each thread owns 8 consecutive p.
// ---------------------------------------------------------------------------
__global__ __launch_bounds__(192) void k_t2_f8(
    const unsigned char* __restrict__ Phi8,
    const float* __restrict__ yr,
    const float* __restrict__ surf_cur,
    const float* __restrict__ clouds_cur,
    const float* __restrict__ rho_base,
    const float* __restrict__ rho_i,
    float* __restrict__ s2t1,
    float* __restrict__ out_clouds_i)
{
    __shared__ float s_yr[M_];
    const int bid = blockIdx.x >> 1;
    const int ph  = blockIdx.x & 1;
    const int b   = bid / E_;
    const int tid = threadIdx.x;

    if (tid < M_) s_yr[tid] = yr[bid * M_ + tid];
    __syncthreads();

    const int p0 = ph * 1536 + tid * 8;
    const unsigned char* phi = Phi8 + (size_t)bid * (M_ * P_) + p0;

    float acc[8] = {0.f, 0.f, 0.f, 0.f, 0.f, 0.f, 0.f, 0.f};
    #pragma unroll 8
    for (int m = 0; m < M_; ++m) {
        const float ym = s_yr[m];
        uint2 w = *reinterpret_cast<const uint2*>(phi + (size_t)m * P_);
        floatx2 l0 = __builtin_amdgcn_cvt_pk_f32_fp8((int)w.x, false);
        floatx2 h0 = __builtin_amdgcn_cvt_pk_f32_fp8((int)w.x, true);
        floatx2 l1 = __builtin_amdgcn_cvt_pk_f32_fp8((int)w.y, false);
        floatx2 h1 = __builtin_amdgcn_cvt_pk_f32_fp8((int)w.y, true);
        acc[0] += l0.x * ym; acc[1] += l0.y * ym; acc[2] += h0.x * ym; acc[3] += h0.y * ym;
        acc[4] += l1.x * ym; acc[5] += l1.y * ym; acc[6] += h1.x * ym; acc[7] += h1.y * ym;
    }
    #pragma unroll
    for (int k = 0; k < 8; ++k) acc[k] *= PHI_INV;

    const float s = rho_base[b] * fminf(fmaxf(*rho_i, 0.1f), 3.0f);
    const size_t gi = (size_t)bid * P_ + p0;
    float4 c0 = *reinterpret_cast<const float4*>(clouds_cur + gi);
    float4 c1 = *reinterpret_cast<const float4*>(clouds_cur + gi + 4);
    const size_t si = (size_t)b * P_ + p0;
    float4 v0 = *reinterpret_cast<const float4*>(surf_cur + si);
    float4 v1 = *reinterpret_cast<const float4*>(surf_cur + si + 4);

    float cl[8] = {c0.x, c0.y, c0.z, c0.w, c1.x, c1.y, c1.z, c1.w};
    float sv[8] = {v0.x, v0.y, v0.z, v0.w, v1.x, v1.y, v1.z, v1.w};
    float st[8], nc[8];
    #pragma unroll
    for (int k = 0; k < 8; ++k) {
        float t0 = 1.f - cl[k];
        st[k] = acc[k] * t0 * t0;
        float gc = 2.f * acc[k] * (1.f - 2.f * sv[k] * t0);
        nc[k] = fmaxf(cl[k] - s * gc, 0.f);
    }
    reinterpret_cast<float4*>(s2t1 + gi)[0] = make_float4(st[0], st[1], st[2], st[3]);
    reinterpret_cast<float4*>(s2t1 + gi + 4)[0] = make_float4(st[4], st[5], st[6], st[7]);
    reinterpret_cast<float4*>(out_clouds_i + gi)[0] = make_float4(nc[0], nc[1], nc[2], nc[3]);
    reinterpret_cast<float4*>(out_clouds_i + gi + 4)[0] = make_float4(nc[4], nc[5], nc[6], nc[7]);
}

// fp32 fallback variant
__global__ __launch_bounds__(192) void k_t2_f32(
    const float* __restrict__ Phi,
    const float* __restrict__ yr,
    const float* __restrict__ surf_cur,
    const float* __restrict__ clouds_cur,
    const float* __restrict__ rho_base,
    const float* __restrict__ rho_i,
    float* __restrict__ s2t1,
    float* __restrict__ out_clouds_i)
{
    __shared__ float s_yr[M_];
    const int bid = blockIdx.x >> 1;
    const int ph  = blockIdx.x & 1;
    const int b   = bid / E_;
    const int tid = threadIdx.x;

    if (tid < M_) s_yr[tid] = yr[bid * M_ + tid];
    __syncthreads();

    const int p0 = ph * 1536 + tid * 8;
    const float* phi = Phi + (size_t)bid * (M_ * P_) + p0;

    float acc[8] = {0.f, 0.f, 0.f, 0.f, 0.f, 0.f, 0.f, 0.f};
    #pragma unroll 4
    for (int m = 0; m < M_; ++m) {
        const float ym = s_yr[m];
        float4 a = *reinterpret_cast<const float4*>(phi + (size_t)m * P_);
        float4 bv = *reinterpret_cast<const float4*>(phi + (size_t)m * P_ + 4);
        acc[0] += a.x * ym; acc[1] += a.y * ym; acc[2] += a.z * ym; acc[3] += a.w * ym;
        acc[4] += bv.x * ym; acc[5] += bv.y * ym; acc[6] += bv.z * ym; acc[7] += bv.w * ym;
    }

    const float s = rho_base[b] * fminf(fmaxf(*rho_i, 0.1f), 3.0f);
    const size_t gi = (size_t)bid * P_ + p0;
    float4 c0 = *reinterpret_cast<const float4*>(clouds_cur + gi);
    float4 c1 = *reinterpret_cast<const float4*>(clouds_cur + gi + 4);
    const size_t si = (size_t)b * P_ + p0;
    float4 v0 = *reinterpret_cast<const float4*>(surf_cur + si);
    float4 v1 = *reinterpret_cast<const float4*>(surf_cur + si + 4);

    float cl[8] = {c0.x, c0.y, c0.z, c0.w, c1.x, c1.y, c1.z, c1.w};
    float sv[8] = {v0.x, v0.y, v0.z, v0.w, v1.x, v1.y, v1.z, v1.w};
    float st[8], nc[8];
    #pragma unroll
    for (int k = 0; k < 8; ++k) {
        float t0 = 1.f - cl[k];
        st[k] = acc[k] * t0 * t0;
        float gc = 2.f * acc[k] * (1.f - 2.f * sv[k] * t0);
        nc[k] = fmaxf(cl[k] - s * gc, 0.f);
    }
    reinterpret_cast<float4*>(s2t1 + gi)[0] = make_float4(st[0], st[1], st[2], st[3]);
    reinterpret_cast<float4*>(s2t1 + gi + 4)[0] = make_float4(st[4], st[5], st[6], st[7]);
    reinterpret_cast<float4*>(out_clouds_i + gi)[0] = make_float4(nc[0], nc[1], nc[2], nc[3]);
    reinterpret_cast<float4*>(out_clouds_i + gi + 4)[0] = make_float4(nc[4], nc[5], nc[6], nc[7]);
}

// ---------------------------------------------------------------------------
// Kernel 2: surf update + prior_surface CNN. One block per (b, P-tile of TT).
// ---------------------------------------------------------------------------
__device__ __forceinline__ void conv32_rt(const float* __restrict__ inb,
                                          float* __restrict__ outb,
                                          const float* __restrict__ w,
                                          const int Wout, const int pstart)
{
    const int tid = threadIdx.x;
    const int QG = (Wout + 3) >> 2;
    const int items = 8 * QG;
    for (int g = tid; g < items; g += 256) {
        const int oo = g / QG;
        const int q  = g - oo * QG;
        const int j0 = q << 2;
        float a[4][4];
        #pragma unroll
        for (int ol = 0; ol < 4; ++ol)
            a[ol][0] = a[ol][1] = a[ol][2] = a[ol][3] = 0.f;
        #pragma unroll 4
        for (int c = 0; c < 32; ++c) {
            const float* ip = inb + c * 400 + j0;
            const float4 i03 = *reinterpret_cast<const float4*>(ip);
            const float2 i45 = *reinterpret_cast<const float2*>(ip + 4);
            const float* wb = w + (c * 32 + oo * 4) * 4;
            #pragma unroll
            for (int ol = 0; ol < 4; ++ol) {
                const float4 wv = *reinterpret_cast<const float4*>(wb + ol * 4);
                a[ol][0] += i03.x * wv.x + i03.y * wv.y + i03.z * wv.z;
                a[ol][1] += i03.y * wv.x + i03.z * wv.y + i03.w * wv.z;
                a[ol][2] += i03.z * wv.x + i03.w * wv.y + i45.x * wv.z;
                a[ol][3] += i03.w * wv.x + i45.x * wv.y + i45.y * wv.z;
            }
        }
        const int p = pstart + j0;
        #pragma unroll
        for (int ol = 0; ol < 4; ++ol) {
            float* op = outb + (oo * 4 + ol) * 400 + j0;
            if (j0     < Wout) op[0] = (p     >= 0 && p     < P_) ? fmaxf(a[ol][0], 0.f) : 0.f;
            if (j0 + 1 < Wout) op[1] = (p + 1 >= 0 && p + 1 < P_) ? fmaxf(a[ol][1], 0.f) : 0.f;
            if (j0 + 2 < Wout) op[2] = (p + 2 >= 0 && p + 2 < P_) ? fmaxf(a[ol][2], 0.f) : 0.f;
            if (j0 + 3 < Wout) op[3] = (p + 3 >= 0 && p + 3 < P_) ? fmaxf(a[ol][3], 0.f) : 0.f;
        }
    }
}

__global__ __launch_bounds__(256) void k_surf(
    const float* __restrict__ surf0,
    const float* __restrict__ surf_cur,
    const float* __restrict__ s2t1,
    const float* __restrict__ rho_base,
    const float* __restrict__ rho_i,
    const float* __restrict__ w1,
    const float* __restrict__ w2,
    const float* __restrict__ w3,
    const float* __restrict__ w4,
    float* __restrict__ out_surface_i)
{
    __shared__ float sx[400];
    __shared__ float bufA[32 * 400];
    __shared__ float bufB[32 * 400];
    __shared__ float sw2s[32 * 32 * 4];   // [c][o][tap4]
    __shared__ float sw3s[32 * 32 * 4];
    __shared__ float sw1s[32 * 4];
    __shared__ float sw4s[32 * 4];

    const int tid = threadIdx.x;
    const int b  = blockIdx.x / NT;
    const int t  = blockIdx.x % NT;
    const int p0 = t * TT;

    for (int i = tid; i < 1024; i += 256) {
        const int c = i >> 5, o = i & 31;
        const int src = (o * 32 + c) * 3;
        sw2s[i * 4 + 0] = w2[src + 0];
        sw2s[i * 4 + 1] = w2[src + 1];
        sw2s[i * 4 + 2] = w2[src + 2];
        sw2s[i * 4 + 3] = 0.f;
        sw3s[i * 4 + 0] = w3[src + 0];
        sw3s[i * 4 + 1] = w3[src + 1];
        sw3s[i * 4 + 2] = w3[src + 2];
        sw3s[i * 4 + 3] = 0.f;
    }
    if (tid < 32) {
        sw1s[tid * 4 + 0] = w1[tid * 3 + 0];
        sw1s[tid * 4 + 1] = w1[tid * 3 + 1];
        sw1s[tid * 4 + 2] = w1[tid * 3 + 2];
        sw1s[tid * 4 + 3] = 0.f;
        sw4s[tid * 4 + 0] = w4[tid * 3 + 0];
        sw4s[tid * 4 + 1] = w4[tid * 3 + 1];
        sw4s[tid * 4 + 2] = w4[tid * 3 + 2];
        sw4s[tid * 4 + 3] = 0.f;
    }
    for (int i = tid; i < 32 * 16; i += 256) {
        const int c = i >> 4, j = 384 + (i & 15);
        bufA[c * 400 + j] = 0.f;
        bufB[c * 400 + j] = 0.f;
    }

    const float s = rho_base[b] * fminf(fmaxf(*rho_i, 0.1f), 3.0f);

    for (int j = tid; j < 400; j += 256) {
        float v = 0.f;
        const int p = p0 + j - 4;
        if (j < TT + 8 && p >= 0 && p < P_) {
            float g = surf0[(size_t)b * P_ + p];
            #pragma unroll
            for (int e = 0; e < E_; ++e)
                g += 2.f * s2t1[((size_t)(b * E_ + e)) * P_ + p];
            v = surf_cur[(size_t)b * P_ + p] - s * g;
        }
        sx[j] = v;
    }
    __syncthreads();

    {
        const int Wout = TT + 6;
        const int QG = (Wout + 3) >> 2;
        const int pstart = p0 - 3;
        for (int g = tid; g < 32 * QG; g += 256) {
            const int o = g / QG;
            const int q = g - o * QG;
            const int j0 = q << 2;
            const float4 i03 = *reinterpret_cast<const float4*>(&sx[j0]);
            const float2 i45 = *reinterpret_cast<const float2*>(&sx[j0 + 4]);
            const float4 wv = *reinterpret_cast<const float4*>(&sw1s[o * 4]);
            float a0 = i03.x * wv.x + i03.y * wv.y + i03.z * wv.z;
            float a1 = i03.y * wv.x + i03.z * wv.y + i03.w * wv.z;
            float a2 = i03.z * wv.x + i03.w * wv.y + i45.x * wv.z;
            float a3 = i03.w * wv.x + i45.x * wv.y + i45.y * wv.z;
            float* op = &bufA[o * 400 + j0];
            const int p = pstart + j0;
            if (j0     < Wout) op[0] = (p     >= 0 && p     < P_) ? fmaxf(a0, 0.f) : 0.f;
            if (j0 + 1 < Wout) op[1] = (p + 1 >= 0 && p + 1 < P_) ? fmaxf(a1, 0.f) : 0.f;
            if (j0 + 2 < Wout) op[2] = (p + 2 >= 0 && p + 2 < P_) ? fmaxf(a2, 0.f) : 0.f;
            if (j0 + 3 < Wout) op[3] = (p + 3 >= 0 && p + 3 < P_) ? fmaxf(a3, 0.f) : 0.f;
        }
    }
    __syncthreads();
    conv32_rt(bufA, bufB, sw2s, TT + 4, p0 - 2);
    __syncthreads();
    conv32_rt(bufB, bufA, sw3s, TT + 2, p0 - 1);
    __syncthreads();

    for (int g = tid; g < TT / 4; g += 256) {
        const int j0 = g << 2;
        float a0 = 0.f, a1 = 0.f, a2 = 0.f, a3 = 0.f;
        #pragma unroll 8
        for (int c = 0; c < 32; ++c) {
            const float* ip = &bufA[c * 400 + j0];
            const float4 i03 = *reinterpret_cast<const float4*>(ip);
            const float2 i45 = *reinterpret_cast<const float2*>(ip + 4);
            const float4 wv = *reinterpret_cast<const float4*>(&sw4s[c * 4]);
            a0 += i03.x * wv.x + i03.y * wv.y + i03.z * wv.z;
            a1 += i03.y * wv.x + i03.z * wv.y + i03.w * wv.z;
            a2 += i03.z * wv.x + i03.w * wv.y + i45.x * wv.z;
            a3 += i03.w * wv.x + i45.x * wv.y + i45.y * wv.z;
        }
        const float4 xr = *reinterpret_cast<const float4*>(&sx[j0 + 4]);
        float4 ov;
        ov.x = fminf(fmaxf(xr.x + fmaxf(a0, 0.f), 0.f), 1.f);
        ov.y = fminf(fmaxf(xr.y + fmaxf(a1, 0.f), 0.f), 1.f);
        ov.z = fminf(fmaxf(xr.z + fmaxf(a2, 0.f), 0.f), 1.f);
        ov.w = fminf(fmaxf(xr.w + fmaxf(a3, 0.f), 0.f), 1.f);
        *reinterpret_cast<float4*>(&out_surface_i[(size_t)b * P_ + p0 + j0]) = ov;
    }
}

// ---------------------------------------------------------------------------
extern "C" void kernel_launch(void* const* d_in, const int* in_sizes, int n_in,
                              void* d_out, int out_size, void* d_ws, size_t ws_size,
                              hipStream_t stream)
{
    (void)in_sizes; (void)n_in; (void)out_size;

    const float* dsplit   = (const float*)d_in[0];
    const float* surf0    = (const float*)d_in[1];
    const float* clouds0  = (const float*)d_in[2];
    const float* Phi      = (const float*)d_in[3];
    const float* rho_base = (const float*)d_in[4];
    const float* rho      = (const float*)d_in[5];
    const float* w1       = (const float*)d_in[6];
    const float* w2       = (const float*)d_in[7];
    const float* w3       = (const float*)d_in[8];
    const float* w4       = (const float*)d_in[9];

    float* out = (float*)d_out;
    float* out_surf_final   = out;                                      // [B,P]
    float* out_clouds_final = out + (size_t)B_ * P_;                    // [B,E,P]
    float* out_surface      = out_clouds_final + (size_t)B_ * E_ * P_;  // [K,B,P]
    float* out_clouds       = out_surface + (size_t)K_ * B_ * P_;       // [K,B,E,P]

    // scratch: yr (B*E*M floats) in the surf_final slot, s2t1 in clouds_final
    // slot; both fully overwritten by the final d2d copies.
    float* yr   = out_surf_final;
    float* s2t1 = out_clouds_final;

    const size_t PHI_N = (size_t)B_ * E_ * M_ * P_;   // 125,829,120 (fp8 bytes)
    const bool use8 = (ws_size >= PHI_N);
    unsigned char* phi8 = (unsigned char*)d_ws;

    for (int i = 0; i < K_; ++i) {
        const float* scur = (i == 0) ? surf0   : out_surface + (size_t)(i - 1) * B_ * P_;
        const float* ccur = (i == 0) ? clouds0 : out_clouds + (size_t)(i - 1) * B_ * E_ * P_;
        float* oc_i = out_clouds + (size_t)i * B_ * E_ * P_;

        if (use8) {
            if (i == 0)
                k_y<1><<<dim3(B_ * E_ * 2), dim3(256), 0, stream>>>(
                    Phi, nullptr, phi8, dsplit, scur, ccur, yr);
            else
                k_y<2><<<dim3(B_ * E_ * 2), dim3(256), 0, stream>>>(
                    nullptr, phi8, nullptr, dsplit, scur, ccur, yr);
            k_t2_f8<<<dim3(B_ * E_ * 2), dim3(192), 0, stream>>>(
                phi8, yr, scur, ccur, rho_base, rho + i, s2t1, oc_i);
        } else {
            k_y<0><<<dim3(B_ * E_ * 2), dim3(256), 0, stream>>>(
                Phi, nullptr, nullptr, dsplit, scur, ccur, yr);
            k_t2_f32<<<dim3(B_ * E_ * 2), dim3(192), 0, stream>>>(
                Phi, yr, scur, ccur, rho_base, rho + i, s2t1, oc_i);
        }

        k_surf<<<dim3(B_ * NT), dim3(256), 0, stream>>>(
            surf0, scur, s2t1, rho_base, rho + i,
            w1 + (size_t)i * 96, w2 + (size_t)i * 3072,
            w3 + (size_t)i * 3072, w4 + (size_t)i * 96,
            out_surface + (size_t)i * B_ * P_);
    }

    hipMemcpyAsync(out_surf_final, out_surface + (size_t)(K_ - 1) * B_ * P_,
                   (size_t)B_ * P_ * sizeof(float), hipMemcpyDeviceToDevice, stream);
    hipMemcpyAsync(out_clouds_final, out_clouds + (size_t)(K_ - 1) * B_ * E_ * P_,
                   (size_t)B_ * E_ * P_ * sizeof(float), hipMemcpyDeviceToDevice, stream);
}

// Round 5
// 904.585 us; speedup vs baseline: 2.6762x; 1.1605x over previous
//
#include <hip/hip_runtime.h>

#define B_ 32
#define E_ 20
#define M_ 64
#define P_ 3072
#define K_ 9
#define BEP (B_ * E_ * P_)     // 1,966,080
#define TT2 192                // CNN tile width
#define NT2 16                 // tiles per batch row
#define BUFW 208               // CNN LDS row stride (192 + 8 halo + slack)

#define PHI_SCALE 65536.0f
#define PHI_INV   (1.0f / 65536.0f)

typedef float floatx2 __attribute__((ext_vector_type(2)));
typedef _Float16 half4v __attribute__((ext_vector_type(4)));

__device__ __forceinline__ unsigned int pack4_fp8(float f0, float f1, float f2, float f3)
{
    int w = 0;
    w = __builtin_amdgcn_cvt_pk_fp8_f32(f0, f1, w, false);
    w = __builtin_amdgcn_cvt_pk_fp8_f32(f2, f3, w, true);
    return (unsigned int)w;
}

// ---------------------------------------------------------------------------
// k_A: fused y -> t2 -> gradient epilogue. One block per (b,e). No grid sync
// needed: t2[b,e] depends only on y[b,e] (block-local, y kept in LDS).
// MODE 0 (iter 0): read fp32 Phi for y, quantize->fp8 on the fly; t2 reads fp8.
// MODE 1 (iters 1..8): read fp8 Phi everywhere.
// ---------------------------------------------------------------------------
template <int MODE>
__global__ __launch_bounds__(256) void k_A(
    const float* __restrict__ PhiF,
    const unsigned char* __restrict__ Phi8,
    unsigned char* __restrict__ Phi8w,
    const float* __restrict__ dsplit,
    const float* __restrict__ surf_cur,
    const float* __restrict__ clouds_cur,
    const float* __restrict__ rho_base,
    const float* __restrict__ rho_i,
    float* __restrict__ s2t1,
    float* __restrict__ out_clouds_i,
    float* __restrict__ out_clouds_final)   // non-null only at i==K-1
{
    __shared__ float s_tmp[P_];
    __shared__ float s_yr[M_];

    const int bid = blockIdx.x;          // b*E_ + e
    const int b   = bid / E_;
    const int tid = threadIdx.x;
    const int wave = tid >> 6, lane = tid & 63;
    const size_t base = (size_t)bid * (M_ * P_);

    const float* ccur = clouds_cur + (size_t)bid * P_;
    const float* scur = surf_cur + (size_t)b * P_;

    // stage tmp = clouds + (1-clouds)^2 * surf
    {
        const float4* cl4 = reinterpret_cast<const float4*>(ccur);
        const float4* sf4 = reinterpret_cast<const float4*>(scur);
        for (int f = tid; f < P_ / 4; f += 256) {
            float4 c4 = cl4[f], s4 = sf4[f], tm;
            float t0x = 1.f - c4.x, t0y = 1.f - c4.y, t0z = 1.f - c4.z, t0w = 1.f - c4.w;
            tm.x = c4.x + t0x * t0x * s4.x;
            tm.y = c4.y + t0y * t0y * s4.y;
            tm.z = c4.z + t0z * t0z * s4.z;
            tm.w = c4.w + t0w * t0w * s4.w;
            reinterpret_cast<float4*>(s_tmp)[f] = tm;
        }
    }
    __syncthreads();

    // ---- pass 1: y[m] - d[m] into LDS (4 waves x 16 rows) ----
    if constexpr (MODE == 0) {
        #pragma unroll 2
        for (int r = 0; r < 16; ++r) {
            const int mg = (wave << 4) + r;
            const float4* prow = reinterpret_cast<const float4*>(PhiF + base + (size_t)mg * P_);
            unsigned int* orow = reinterpret_cast<unsigned int*>(Phi8w + base + (size_t)mg * P_);
            float acc = 0.f;
            #pragma unroll
            for (int j = 0; j < 12; ++j) {
                const int f = j * 64 + lane;
                float4 v = prow[f];
                float4 t = reinterpret_cast<const float4*>(s_tmp)[f];
                acc += v.x * t.x + v.y * t.y + v.z * t.z + v.w * t.w;
                orow[f] = pack4_fp8(v.x * PHI_SCALE, v.y * PHI_SCALE,
                                    v.z * PHI_SCALE, v.w * PHI_SCALE);
            }
            #pragma unroll
            for (int off = 32; off > 0; off >>= 1)
                acc += __shfl_down(acc, off, 64);
            if (lane == 0)
                s_yr[mg] = acc - dsplit[bid * M_ + mg];
        }
    } else {
        #pragma unroll 2
        for (int r = 0; r < 16; ++r) {
            const int mg = (wave << 4) + r;
            const uint2* prow = reinterpret_cast<const uint2*>(Phi8 + base + (size_t)mg * P_);
            float acc = 0.f;
            #pragma unroll
            for (int j = 0; j < 6; ++j) {
                const int f = j * 64 + lane;
                uint2 w = prow[f];
                floatx2 l0 = __builtin_amdgcn_cvt_pk_f32_fp8((int)w.x, false);
                floatx2 h0 = __builtin_amdgcn_cvt_pk_f32_fp8((int)w.x, true);
                floatx2 l1 = __builtin_amdgcn_cvt_pk_f32_fp8((int)w.y, false);
                floatx2 h1 = __builtin_amdgcn_cvt_pk_f32_fp8((int)w.y, true);
                const float4 a  = reinterpret_cast<const float4*>(s_tmp)[2 * f];
                const float4 bb = reinterpret_cast<const float4*>(s_tmp)[2 * f + 1];
                acc += l0.x * a.x + l0.y * a.y + h0.x * a.z + h0.y * a.w
                     + l1.x * bb.x + l1.y * bb.y + h1.x * bb.z + h1.y * bb.w;
            }
            #pragma unroll
            for (int off = 32; off > 0; off >>= 1)
                acc += __shfl_down(acc, off, 64);
            if (lane == 0)
                s_yr[mg] = acc * PHI_INV - dsplit[bid * M_ + mg];
        }
    }
    __syncthreads();   // drains vmcnt: phi8 stores (MODE 0) visible via L2

    // ---- pass 2: t2 (each thread owns 12 consecutive p) + epilogue ----
    {
        const unsigned char* p8 = ((MODE == 0) ? Phi8w : Phi8) + base + tid * 12;
        float acc[12];
        #pragma unroll
        for (int k = 0; k < 12; ++k) acc[k] = 0.f;
        #pragma unroll 4
        for (int m = 0; m < M_; ++m) {
            const float ym = s_yr[m];
            uint3 w = *reinterpret_cast<const uint3*>(p8 + (size_t)m * P_);
            floatx2 c0 = __builtin_amdgcn_cvt_pk_f32_fp8((int)w.x, false);
            floatx2 c1 = __builtin_amdgcn_cvt_pk_f32_fp8((int)w.x, true);
            floatx2 c2 = __builtin_amdgcn_cvt_pk_f32_fp8((int)w.y, false);
            floatx2 c3 = __builtin_amdgcn_cvt_pk_f32_fp8((int)w.y, true);
            floatx2 c4 = __builtin_amdgcn_cvt_pk_f32_fp8((int)w.z, false);
            floatx2 c5 = __builtin_amdgcn_cvt_pk_f32_fp8((int)w.z, true);
            acc[0] += c0.x * ym; acc[1]  += c0.y * ym;
            acc[2] += c1.x * ym; acc[3]  += c1.y * ym;
            acc[4] += c2.x * ym; acc[5]  += c2.y * ym;
            acc[6] += c3.x * ym; acc[7]  += c3.y * ym;
            acc[8] += c4.x * ym; acc[9]  += c4.y * ym;
            acc[10]+= c5.x * ym; acc[11] += c5.y * ym;
        }

        const float s = rho_base[b] * fminf(fmaxf(*rho_i, 0.1f), 3.0f);
        const int p0t = tid * 12;
        const size_t gi = (size_t)bid * P_ + p0t;
        #pragma unroll
        for (int k4 = 0; k4 < 3; ++k4) {
            float4 cv = *reinterpret_cast<const float4*>(ccur + p0t + k4 * 4);
            float4 sv = *reinterpret_cast<const float4*>(scur + p0t + k4 * 4);
            float4 stv, ncv;
#define EPI(C, KK)                                                      \
            {                                                           \
                float t2v = acc[k4 * 4 + KK] * PHI_INV;                 \
                float t0  = 1.f - cv.C;                                 \
                stv.C = t2v * t0 * t0;                                  \
                float gc = 2.f * t2v * (1.f - 2.f * sv.C * t0);         \
                ncv.C = fmaxf(cv.C - s * gc, 0.f);                      \
            }
            EPI(x, 0) EPI(y, 1) EPI(z, 2) EPI(w, 3)
#undef EPI
            *reinterpret_cast<float4*>(s2t1 + gi + k4 * 4) = stv;
            *reinterpret_cast<float4*>(out_clouds_i + gi + k4 * 4) = ncv;
            if (out_clouds_final)
                *reinterpret_cast<float4*>(out_clouds_final + gi + k4 * 4) = ncv;
        }
    }
}

// ---------------------------------------------------------------------------
// k_surf: surf update + prior_surface CNN. 512 blocks = 32 b x 16 tiles of 192.
// fp32 activations, fp16 weights for conv2/conv3 (LDS 71.5 KB -> 2 blocks/CU).
// ---------------------------------------------------------------------------
__global__ __launch_bounds__(256) void k_surf(
    const float* __restrict__ surf0,
    const float* __restrict__ surf_cur,
    const float* __restrict__ s2t1,
    const float* __restrict__ rho_base,
    const float* __restrict__ rho_i,
    const float* __restrict__ w1,
    const float* __restrict__ w2,
    const float* __restrict__ w3,
    const float* __restrict__ w4,
    float* __restrict__ out_surface_i,
    float* __restrict__ out_surf_final)   // non-null only at i==K-1
{
    __shared__ float sx[BUFW];
    __shared__ float bufA[32 * BUFW];
    __shared__ float bufB[32 * BUFW];
    __shared__ _Float16 sw2h[32 * 32 * 4];   // [c][o][tap4]
    __shared__ _Float16 sw3h[32 * 32 * 4];
    __shared__ float sw1s[32 * 4];
    __shared__ float sw4s[32 * 4];

    const int tid = threadIdx.x;
    const int b  = blockIdx.x >> 4;
    const int p0 = (blockIdx.x & 15) * TT2;
    const size_t bP = (size_t)b * P_;

    for (int idx = tid; idx < 1024; idx += 256) {
        const int c = idx >> 5, o = idx & 31;
        const int src = (o * 32 + c) * 3;
        sw2h[idx * 4 + 0] = (_Float16)w2[src + 0];
        sw2h[idx * 4 + 1] = (_Float16)w2[src + 1];
        sw2h[idx * 4 + 2] = (_Float16)w2[src + 2];
        sw2h[idx * 4 + 3] = (_Float16)0.f;
        sw3h[idx * 4 + 0] = (_Float16)w3[src + 0];
        sw3h[idx * 4 + 1] = (_Float16)w3[src + 1];
        sw3h[idx * 4 + 2] = (_Float16)w3[src + 2];
        sw3h[idx * 4 + 3] = (_Float16)0.f;
    }
    if (tid < 32) {
        sw1s[tid * 4 + 0] = w1[tid * 3 + 0];
        sw1s[tid * 4 + 1] = w1[tid * 3 + 1];
        sw1s[tid * 4 + 2] = w1[tid * 3 + 2];
        sw1s[tid * 4 + 3] = 0.f;
        sw4s[tid * 4 + 0] = w4[tid * 3 + 0];
        sw4s[tid * 4 + 1] = w4[tid * 3 + 1];
        sw4s[tid * 4 + 2] = w4[tid * 3 + 2];
        sw4s[tid * 4 + 3] = 0.f;
    }

    const float s = rho_base[b] * fminf(fmaxf(*rho_i, 0.1f), 3.0f);

    // r_surf with halo 4, zero outside [0,P); sx[200..207] zeroed
    for (int j = tid; j < BUFW; j += 256) {
        float v = 0.f;
        const int p = p0 + j - 4;
        if (j < TT2 + 8 && p >= 0 && p < P_) {
            float g = surf0[bP + p];
            #pragma unroll
            for (int e = 0; e < E_; ++e)
                g += 2.f * s2t1[((size_t)(b * E_ + e)) * P_ + p];
            v = surf_cur[bP + p] - s * g;
        }
        sx[j] = v;
    }
    __syncthreads();

    // conv1: sx (width 200, start p0-4) -> bufA (width 198, start p0-3)
    {
        const int Wout = TT2 + 6;      // 198
        const int QG = 50;
        const int pstart = p0 - 3;
        for (int g = tid; g < 32 * QG; g += 256) {
            const int o = g / QG, q = g - o * QG, j0 = q << 2;
            const float4 i03 = *reinterpret_cast<const float4*>(&sx[j0]);
            const float2 i45 = *reinterpret_cast<const float2*>(&sx[j0 + 4]);
            const float4 wv = *reinterpret_cast<const float4*>(&sw1s[o * 4]);
            float a0 = i03.x * wv.x + i03.y * wv.y + i03.z * wv.z;
            float a1 = i03.y * wv.x + i03.z * wv.y + i03.w * wv.z;
            float a2 = i03.z * wv.x + i03.w * wv.y + i45.x * wv.z;
            float a3 = i03.w * wv.x + i45.x * wv.y + i45.y * wv.z;
            float* op = &bufA[o * BUFW + j0];
            const int p = pstart + j0;
            if (j0     < Wout) op[0] = (p     >= 0 && p     < P_) ? fmaxf(a0, 0.f) : 0.f;
            if (j0 + 1 < Wout) op[1] = (p + 1 >= 0 && p + 1 < P_) ? fmaxf(a1, 0.f) : 0.f;
            if (j0 + 2 < Wout) op[2] = (p + 2 >= 0 && p + 2 < P_) ? fmaxf(a2, 0.f) : 0.f;
            if (j0 + 3 < Wout) op[3] = (p + 3 >= 0 && p + 3 < P_) ? fmaxf(a3, 0.f) : 0.f;
        }
    }
    __syncthreads();

    // conv2 / conv3: register-tiled 4 o x 4 j, fp16 weights
    for (int layer = 0; layer < 2; ++layer) {
        const float* inb  = layer ? bufB : bufA;
        float* outb       = layer ? bufA : bufB;
        const _Float16* w = layer ? sw3h : sw2h;
        const int Wout    = layer ? (TT2 + 2) : (TT2 + 4);
        const int pstart  = layer ? (p0 - 1) : (p0 - 2);
        const int QG = (Wout + 3) >> 2;
        for (int g = tid; g < 8 * QG; g += 256) {
            const int oo = g / QG, q = g - oo * QG, j0 = q << 2;
            float a[4][4];
            #pragma unroll
            for (int ol = 0; ol < 4; ++ol)
                a[ol][0] = a[ol][1] = a[ol][2] = a[ol][3] = 0.f;
            #pragma unroll 4
            for (int c = 0; c < 32; ++c) {
                const float* ip = inb + c * BUFW + j0;
                const float4 i03 = *reinterpret_cast<const float4*>(ip);
                const float2 i45 = *reinterpret_cast<const float2*>(ip + 4);
                const float f0 = i03.x, f1 = i03.y, f2 = i03.z,
                            f3 = i03.w, f4 = i45.x, f5 = i45.y;
                const _Float16* wb = w + (c * 32 + oo * 4) * 4;
                #pragma unroll
                for (int ol = 0; ol < 4; ++ol) {
                    half4v wv = *reinterpret_cast<const half4v*>(wb + ol * 4);
                    const float w0 = wv[0], w1v = wv[1], w2v = wv[2];
                    a[ol][0] += f0 * w0 + f1 * w1v + f2 * w2v;
                    a[ol][1] += f1 * w0 + f2 * w1v + f3 * w2v;
                    a[ol][2] += f2 * w0 + f3 * w1v + f4 * w2v;
                    a[ol][3] += f3 * w0 + f4 * w1v + f5 * w2v;
                }
            }
            const int p = pstart + j0;
            #pragma unroll
            for (int ol = 0; ol < 4; ++ol) {
                float* op = outb + (oo * 4 + ol) * BUFW + j0;
                if (j0     < Wout) op[0] = (p     >= 0 && p     < P_) ? fmaxf(a[ol][0], 0.f) : 0.f;
                if (j0 + 1 < Wout) op[1] = (p + 1 >= 0 && p + 1 < P_) ? fmaxf(a[ol][1], 0.f) : 0.f;
                if (j0 + 2 < Wout) op[2] = (p + 2 >= 0 && p + 2 < P_) ? fmaxf(a[ol][2], 0.f) : 0.f;
                if (j0 + 3 < Wout) op[3] = (p + 3 >= 0 && p + 3 < P_) ? fmaxf(a[ol][3], 0.f) : 0.f;
            }
        }
        __syncthreads();
    }

    // conv4 + residual + clip
    {
        float* orow = out_surface_i + bP + p0;
        for (int g = tid; g < TT2 / 2; g += 256) {
            const int j0 = g * 2;
            float a0 = 0.f, a1 = 0.f;
            #pragma unroll 8
            for (int c = 0; c < 32; ++c) {
                const float* ip = &bufA[c * BUFW + j0];
                const float2 iA = *reinterpret_cast<const float2*>(ip);
                const float2 iB = *reinterpret_cast<const float2*>(ip + 2);
                const float4 wv = *reinterpret_cast<const float4*>(&sw4s[c * 4]);
                a0 += iA.x * wv.x + iA.y * wv.y + iB.x * wv.z;
                a1 += iA.y * wv.x + iB.x * wv.y + iB.y * wv.z;
            }
            const float x0 = sx[j0 + 4], x1 = sx[j0 + 5];
            float2 ov;
            ov.x = fminf(fmaxf(x0 + fmaxf(a0, 0.f), 0.f), 1.f);
            ov.y = fminf(fmaxf(x1 + fmaxf(a1, 0.f), 0.f), 1.f);
            *reinterpret_cast<float2*>(orow + j0) = ov;
            if (out_surf_final)
                *reinterpret_cast<float2*>(out_surf_final + bP + p0 + j0) = ov;
        }
    }
}

// ---------------------------------------------------------------------------
extern "C" void kernel_launch(void* const* d_in, const int* in_sizes, int n_in,
                              void* d_out, int out_size, void* d_ws, size_t ws_size,
                              hipStream_t stream)
{
    (void)in_sizes; (void)n_in; (void)out_size; (void)ws_size;

    const float* dsplit   = (const float*)d_in[0];
    const float* surf0    = (const float*)d_in[1];
    const float* clouds0  = (const float*)d_in[2];
    const float* Phi      = (const float*)d_in[3];
    const float* rho_base = (const float*)d_in[4];
    const float* rho      = (const float*)d_in[5];
    const float* w1       = (const float*)d_in[6];
    const float* w2       = (const float*)d_in[7];
    const float* w3       = (const float*)d_in[8];
    const float* w4       = (const float*)d_in[9];

    float* out = (float*)d_out;
    float* out_surf_final   = out;                                      // [B,P]
    float* out_clouds_final = out + (size_t)B_ * P_;                    // [B,E,P]
    float* out_surface      = out_clouds_final + (size_t)BEP;           // [K,B,P]
    float* out_clouds       = out_surface + (size_t)K_ * B_ * P_;       // [K,B,E,P]

    // workspace: phi8 (125,829,120 B) + s2t1 (7,864,320 B). ws >= 252 MB
    // established empirically (rounds 2/3 quantized paths executed).
    unsigned char* phi8 = (unsigned char*)d_ws;
    float* s2t1 = (float*)((unsigned char*)d_ws + (size_t)B_ * E_ * M_ * P_);

    for (int i = 0; i < K_; ++i) {
        const float* scur = (i == 0) ? surf0   : out_surface + (size_t)(i - 1) * B_ * P_;
        const float* ccur = (i == 0) ? clouds0 : out_clouds + (size_t)(i - 1) * BEP;
        float* oc_i = out_clouds + (size_t)i * BEP;
        float* ocF  = (i == K_ - 1) ? out_clouds_final : nullptr;
        float* osF  = (i == K_ - 1) ? out_surf_final : nullptr;

        if (i == 0)
            k_A<0><<<dim3(B_ * E_), dim3(256), 0, stream>>>(
                Phi, nullptr, phi8, dsplit, scur, ccur,
                rho_base, rho + i, s2t1, oc_i, ocF);
        else
            k_A<1><<<dim3(B_ * E_), dim3(256), 0, stream>>>(
                nullptr, phi8, nullptr, dsplit, scur, ccur,
                rho_base, rho + i, s2t1, oc_i, ocF);

        k_surf<<<dim3(B_ * NT2), dim3(256), 0, stream>>>(
            surf0, scur, s2t1, rho_base, rho + i,
            w1 + (size_t)i * 96, w2 + (size_t)i * 3072,
            w3 + (size_t)i * 3072, w4 + (size_t)i * 96,
            out_surface + (size_t)i * B_ * P_, osF);
    }
}